// Round 1
// baseline (3918.660 us; speedup 1.0000x reference)
//
#include <hip/hip_runtime.h>
#include <hip/hip_bf16.h>
#include <cstdint>

// ---------------------------------------------------------------------------
// LSTM  B=64 T=512 I=512 H=512
// Phase 0: convert/transpose inputs -> bf16 (xp-row order), build W_cat^T bf16,
//          b_cat f32, U pre-swizzled into MFMA B-fragment order.
// Phase 1: x_proj GEMM [32768,512]@[512,2048] bf16 MFMA, bias folded in.
// Phase 2: persistent recurrence: 64 WGs = 4 batch-groups x 16 hidden-slices.
//          U slice lives in REGISTERS (B-frags), h exchanged via global
//          double-buffer + per-WG release/acquire flags.
// Column convention everywhere: c = h_unit*4 + gate   (gate: 0=i,1=f,2=o,3=c)
// ---------------------------------------------------------------------------

typedef __bf16 bf16;
typedef __bf16 bf16x8 __attribute__((ext_vector_type(8)));
typedef float floatx4 __attribute__((ext_vector_type(4)));

#define T_STEPS 512

// ws layout (bytes)
#define XP_OFF     0ull                        // bf16 [T*B][2048]  = 128 MB
#define XBF_OFF    134217728ull                // bf16 [T*B][512]   = 32 MB
#define WCT_OFF    167772160ull                // bf16 [2048][512]  (W_cat^T[c][k]) = 2 MB
#define USW_OFF    169869312ull                // bf16 swizzled U B-frags = 2 MB
#define BCAT_OFF   171966464ull                // f32  [2048]
#define HBUF_OFF   171974656ull                // bf16 [2][4][16][512] = 128 KB
#define FLAGS_OFF  172105728ull                // u32  [64]

// ---------------- K0a: inputs f32 [B][T][I] -> x_bf bf16 in row order (t*64+b)
__global__ void k0a_convert(const float* __restrict__ in, bf16* __restrict__ xbf) {
    int o = blockIdx.x * 256 + threadIdx.x;      // [0, 32768*512)
    int k = o & 511;
    int r = o >> 9;                               // xp row = t*64+b
    int t = r >> 6, b = r & 63;
    xbf[o] = (bf16)in[(b * 512 + t) * 512 + k];
}

// ---------------- K0b: W_cat^T[c][k] bf16 (c = h*4+gate) and b_cat f32
__global__ void k0b_wcat(const float* __restrict__ Wi, const float* __restrict__ Wf,
                         const float* __restrict__ Wo, const float* __restrict__ Wc,
                         const float* __restrict__ bi, const float* __restrict__ bfv,
                         const float* __restrict__ bo, const float* __restrict__ bc,
                         bf16* __restrict__ wct, float* __restrict__ bcat) {
    int o = blockIdx.x * 256 + threadIdx.x;      // [0, 2048*512) ; o = c*512 + k
    int k = o & 511;
    int c = o >> 9;
    int h = c >> 2, g = c & 3;
    const float* W = (g == 0) ? Wi : (g == 1) ? Wf : (g == 2) ? Wo : Wc;
    wct[o] = (bf16)W[k * 512 + h];
    if (o < 2048) {
        int hh = o >> 2, gg = o & 3;
        const float* bv = (gg == 0) ? bi : (gg == 1) ? bfv : (gg == 2) ? bo : bc;
        bcat[o] = bv[hh];
    }
}

// ---------------- K0c: U pre-swizzled into B-fragment order for phase 2.
// element index o = ((((s*4+w)*2+nt)*16+ks)*64+lane)*8+e
// maps to U_gate[k][h] with k=ks*32+(lane>>4)*8+e, col_local=(2w+nt)*16+(lane&15)
__global__ void k0c_uswz(const float* __restrict__ Ui, const float* __restrict__ Uf,
                         const float* __restrict__ Uo, const float* __restrict__ Uc,
                         bf16* __restrict__ usw) {
    int o = blockIdx.x * 256 + threadIdx.x;      // [0, 1048576)
    int e  = o & 7;
    int l  = (o >> 3) & 63;
    int ks = (o >> 9) & 15;
    int nt = (o >> 13) & 1;
    int w  = (o >> 14) & 3;
    int s  = o >> 16;                             // [0,16)
    int k = ks * 32 + (l >> 4) * 8 + e;
    int col_local = (2 * w + nt) * 16 + (l & 15); // [0,128)
    int h = s * 32 + (col_local >> 2);
    int g = col_local & 3;
    const float* U = (g == 0) ? Ui : (g == 1) ? Uf : (g == 2) ? Uo : Uc;
    usw[o] = (bf16)U[k * 512 + h];
}

// ---------------- K1: xp = x_bf @ W_cat + b_cat   (bf16 out)
// 128x128 tile, BK=32, 256 threads (2x2 waves, each 64x64 = 4x4 MFMA tiles).
// LDS rows padded 32->40 elems to break frag-read bank conflicts.
__launch_bounds__(256, 2)
__global__ void k1_gemm(const bf16* __restrict__ xbf, const bf16* __restrict__ wct,
                        const float* __restrict__ bcat, bf16* __restrict__ xp) {
    __shared__ bf16 As[128 * 40];
    __shared__ bf16 Bs[128 * 40];
    int tid = threadIdx.x;
    int wid = tid >> 6, lane = tid & 63;
    int q = lane >> 4, m = lane & 15;
    int wr = wid >> 1, wc = wid & 1;
    int br = blockIdx.x & 255, bc = blockIdx.x >> 8;

    floatx4 acc[4][4] = {};

    for (int kk = 0; kk < 16; ++kk) {
        #pragma unroll
        for (int cc = 0; cc < 2; ++cc) {
            int ch = tid + cc * 256;              // 0..511
            int row = ch >> 2, part = ch & 3;     // 4 x 16B chunks per row
            bf16x8 va = *(const bf16x8*)&xbf[(br * 128 + row) * 512 + kk * 32 + part * 8];
            bf16x8 vb = *(const bf16x8*)&wct[(bc * 128 + row) * 512 + kk * 32 + part * 8];
            *(bf16x8*)&As[row * 40 + part * 8] = va;
            *(bf16x8*)&Bs[row * 40 + part * 8] = vb;
        }
        __syncthreads();
        bf16x8 af[4], bfr[4];
        #pragma unroll
        for (int i = 0; i < 4; ++i) {
            af[i]  = *(const bf16x8*)&As[(wr * 64 + i * 16 + m) * 40 + q * 8];
            bfr[i] = *(const bf16x8*)&Bs[(wc * 64 + i * 16 + m) * 40 + q * 8];
        }
        #pragma unroll
        for (int mt = 0; mt < 4; ++mt)
            #pragma unroll
            for (int nt = 0; nt < 4; ++nt)
                acc[mt][nt] = __builtin_amdgcn_mfma_f32_16x16x32_bf16(
                    af[mt], bfr[nt], acc[mt][nt], 0, 0, 0);
        __syncthreads();
    }
    // epilogue: + bias, cast bf16.  C/D layout: col=lane&15, row=q*4+r
    #pragma unroll
    for (int nt = 0; nt < 4; ++nt) {
        int C = bc * 128 + wc * 64 + nt * 16 + m;
        float bias = bcat[C];
        #pragma unroll
        for (int mt = 0; mt < 4; ++mt) {
            #pragma unroll
            for (int r = 0; r < 4; ++r) {
                int R = br * 128 + wr * 64 + mt * 16 + q * 4 + r;
                xp[(long)R * 2048 + C] = (bf16)(acc[mt][nt][r] + bias);
            }
        }
    }
}

// ---------------- K2: persistent recurrence.
// 64 blocks x 256 threads. block = (bg = blockIdx&3, s = blockIdx>>2).
// Each WG: batch rows [bg*16, bg*16+16), gate-cols [s*128, s*128+128).
// U B-frags in registers (bfr[2][16]). h exchange: hbuf[parity][bg][16][512] bf16.
__launch_bounds__(256, 1)
__global__ void k2_rec(const bf16* __restrict__ xp, const bf16* __restrict__ usw,
                       bf16* __restrict__ hbuf, uint32_t* __restrict__ flags,
                       float* __restrict__ out) {
    __shared__ bf16 h_lds[16 * 520];              // padded 512->520 (2-way banks)
    __shared__ float g_lds[128 * 20];             // [col_local][row], padded 16->20

    int tid = threadIdx.x;
    int wid = tid >> 6, lane = tid & 63;
    int q = lane >> 4, m = lane & 15;
    int bg = blockIdx.x & 3, s = blockIdx.x >> 2;

    // load U B-fragments into registers (one-time, reused all 512 steps)
    bf16x8 bfr[2][16];
    {
        const bf16x8* base = (const bf16x8*)usw;
        #pragma unroll
        for (int nt = 0; nt < 2; ++nt)
            #pragma unroll
            for (int ks = 0; ks < 16; ++ks)
                bfr[nt][ks] = base[(((s * 4 + wid) * 2 + nt) * 16 + ks) * 64 + lane];
    }

    // per-thread cell state: unit u = (row, j): row0 = tid>>5 in [0,8), row1 = +8
    float cst0 = 0.f, cst1 = 0.f;
    int j0 = tid & 31, row0 = tid >> 5, row1 = row0 + 8;

    uint32_t* gflags = flags + bg * 16;

    for (int t = 0; t < T_STEPS; ++t) {
        // prefetch xp (bias already folded) in C-frag layout — independent of h
        float xpv[2][4];
        #pragma unroll
        for (int nt = 0; nt < 2; ++nt) {
            int Cg = s * 128 + (2 * wid + nt) * 16 + m;
            #pragma unroll
            for (int r = 0; r < 4; ++r) {
                int R = t * 64 + bg * 16 + q * 4 + r;
                xpv[nt][r] = (float)xp[(long)R * 2048 + Cg];
            }
        }
        floatx4 acc[2];
        #pragma unroll
        for (int nt = 0; nt < 2; ++nt) {
            acc[nt][0] = xpv[nt][0]; acc[nt][1] = xpv[nt][1];
            acc[nt][2] = xpv[nt][2]; acc[nt][3] = xpv[nt][3];
        }

        if (t > 0) {
            // wait until all 16 slices of this batch group published h_{t-1}
            uint32_t tgt = (uint32_t)t;
            while (true) {
                uint32_t v = 0xFFFFFFFFu;
                if (lane < 16)
                    v = __hip_atomic_load(&gflags[lane], __ATOMIC_ACQUIRE,
                                          __HIP_MEMORY_SCOPE_AGENT);
                if (__all((int)(v >= tgt))) break;
                __builtin_amdgcn_s_sleep(2);
            }
            // stage h_{t-1} [16][512] bf16 -> padded LDS
            const bf16* hsrc = hbuf + (((long)((t - 1) & 1) * 4 + bg) << 13);
            #pragma unroll
            for (int cc = 0; cc < 4; ++cc) {
                int ch = tid + cc * 256;          // 0..1023 chunks of 16B
                int hrow = ch >> 6, coff = ch & 63;
                bf16x8 v8 = *(const bf16x8*)&hsrc[hrow * 512 + coff * 8];
                *(bf16x8*)&h_lds[hrow * 520 + coff * 8] = v8;
            }
            __syncthreads();
            // g += h_{t-1} @ U_slice : A-frag row=m, k=ks*32+q*8..+8
            #pragma unroll
            for (int ks = 0; ks < 16; ++ks) {
                bf16x8 a = *(const bf16x8*)&h_lds[m * 520 + ks * 32 + q * 8];
                acc[0] = __builtin_amdgcn_mfma_f32_16x16x32_bf16(a, bfr[0][ks], acc[0], 0, 0, 0);
                acc[1] = __builtin_amdgcn_mfma_f32_16x16x32_bf16(a, bfr[1][ks], acc[1], 0, 0, 0);
            }
        }

        // scatter g to LDS: g_lds[col_local][row]
        #pragma unroll
        for (int nt = 0; nt < 2; ++nt) {
            int col = (2 * wid + nt) * 16 + m;
            *(floatx4*)&g_lds[col * 20 + q * 4] = acc[nt];
        }
        __syncthreads();

        // elementwise gates: 2 units per thread (rows row0, row1; hidden j0)
        bf16* hdst = hbuf + (((long)(t & 1) * 4 + bg) << 13);
        {
            float gi = g_lds[(j0 * 4 + 0) * 20 + row0];
            float gf = g_lds[(j0 * 4 + 1) * 20 + row0];
            float go = g_lds[(j0 * 4 + 2) * 20 + row0];
            float gc = g_lds[(j0 * 4 + 3) * 20 + row0];
            float ig = 1.f / (1.f + __expf(-gi));
            float fg = 1.f / (1.f + __expf(-gf));
            float og = 1.f / (1.f + __expf(-go));
            float th = 1.f - 2.f / (__expf(2.f * gc) + 1.f);
            cst0 = fg * cst0 + ig * th;
            float hv = og * (1.f - 2.f / (__expf(2.f * cst0) + 1.f));
            hdst[row0 * 512 + s * 32 + j0] = (bf16)hv;
            if (t == T_STEPS - 1) out[(bg * 16 + row0) * 512 + s * 32 + j0] = hv;
        }
        {
            float gi = g_lds[(j0 * 4 + 0) * 20 + row1];
            float gf = g_lds[(j0 * 4 + 1) * 20 + row1];
            float go = g_lds[(j0 * 4 + 2) * 20 + row1];
            float gc = g_lds[(j0 * 4 + 3) * 20 + row1];
            float ig = 1.f / (1.f + __expf(-gi));
            float fg = 1.f / (1.f + __expf(-gf));
            float og = 1.f / (1.f + __expf(-go));
            float th = 1.f - 2.f / (__expf(2.f * gc) + 1.f);
            cst1 = fg * cst1 + ig * th;
            float hv = og * (1.f - 2.f / (__expf(2.f * cst1) + 1.f));
            hdst[row1 * 512 + s * 32 + j0] = (bf16)hv;
            if (t == T_STEPS - 1) out[(bg * 16 + row1) * 512 + s * 32 + j0] = hv;
        }
        __syncthreads();   // all h stores done (drains vmcnt) before publish

        if (tid == 0) {
            __threadfence();  // agent release: flush XCD L2 so other XCDs see h
            __hip_atomic_store(&gflags[s], (uint32_t)(t + 1), __ATOMIC_RELEASE,
                               __HIP_MEMORY_SCOPE_AGENT);
        }
    }
}

// ---------------------------------------------------------------------------
extern "C" void kernel_launch(void* const* d_in, const int* in_sizes, int n_in,
                              void* d_out, int out_size, void* d_ws, size_t ws_size,
                              hipStream_t stream) {
    const float* inp = (const float*)d_in[0];
    const float* Wi  = (const float*)d_in[1];
    const float* Wf  = (const float*)d_in[2];
    const float* Wo  = (const float*)d_in[3];
    const float* Wc  = (const float*)d_in[4];
    const float* Ui  = (const float*)d_in[5];
    const float* Uf  = (const float*)d_in[6];
    const float* Uo  = (const float*)d_in[7];
    const float* Uc  = (const float*)d_in[8];
    const float* bi  = (const float*)d_in[9];
    const float* bfv = (const float*)d_in[10];
    const float* bo  = (const float*)d_in[11];
    const float* bc  = (const float*)d_in[12];

    char* ws = (char*)d_ws;
    bf16*  xp    = (bf16*)(ws + XP_OFF);
    bf16*  xbf   = (bf16*)(ws + XBF_OFF);
    bf16*  wct   = (bf16*)(ws + WCT_OFF);
    bf16*  usw   = (bf16*)(ws + USW_OFF);
    float* bcat  = (float*)(ws + BCAT_OFF);
    bf16*  hbuf  = (bf16*)(ws + HBUF_OFF);
    uint32_t* flags = (uint32_t*)(ws + FLAGS_OFF);

    hipMemsetAsync(flags, 0, 64 * sizeof(uint32_t), stream);

    k0a_convert<<<65536, 256, 0, stream>>>(inp, xbf);
    k0b_wcat<<<4096, 256, 0, stream>>>(Wi, Wf, Wo, Wc, bi, bfv, bo, bc, wct, bcat);
    k0c_uswz<<<4096, 256, 0, stream>>>(Ui, Uf, Uo, Uc, usw);
    k1_gemm<<<4096, 256, 0, stream>>>(xbf, wct, bcat, xp);
    k2_rec<<<64, 256, 0, stream>>>(xp, usw, hbuf, flags, (float*)d_out);
}

// Round 2
// 2884.373 us; speedup vs baseline: 1.3586x; 1.3586x over previous
//
#include <hip/hip_runtime.h>
#include <hip/hip_bf16.h>
#include <cstdint>

// ---------------------------------------------------------------------------
// LSTM  B=64 T=512 I=512 H=512
// Phase 0: convert/transpose inputs -> bf16, W_cat^T bf16, b_cat f32,
//          U pre-swizzled into MFMA B-fragment order.
// Phase 1: x_proj GEMM [32768,512]@[512,2048] bf16 MFMA, bias folded in.
// Phase 2: persistent recurrence: 64 WGs = 4 batch-groups x 16 hidden-slices.
//          U slice in registers. h exchanged via WRITE-THROUGH agent-scope
//          atomics (no L2 flush, no threadfence): relaxed atomic stores of
//          packed bf16x2, relaxed atomic u64 loads straight into A-frags.
// Column convention: c = h_unit*4 + gate   (gate: 0=i,1=f,2=o,3=c)
// ---------------------------------------------------------------------------

typedef __bf16 bf16;
typedef __bf16 bf16x8 __attribute__((ext_vector_type(8)));
typedef float floatx4 __attribute__((ext_vector_type(4)));
typedef uint64_t u64;

#define T_STEPS 512

// ws layout (bytes)
#define XP_OFF     0ull                        // bf16 [T*B][2048]  = 128 MB
#define XBF_OFF    134217728ull                // bf16 [T*B][512]   = 32 MB
#define WCT_OFF    167772160ull                // bf16 [2048][512]  = 2 MB
#define USW_OFF    169869312ull                // bf16 swizzled U B-frags = 2 MB
#define BCAT_OFF   171966464ull                // f32  [2048]
#define HBUF_OFF   171974656ull                // u32  [2][4][16][256] = 128 KB
#define FLAGS_OFF  172105728ull                // u32  [64]

__device__ inline uint32_t pack_bf16x2(float a, float b) {
    union { __bf16 h[2]; uint32_t u; } cv;
    cv.h[0] = (__bf16)a; cv.h[1] = (__bf16)b;
    return cv.u;
}

// ---------------- K0a: inputs f32 [B][T][I] -> x_bf bf16 in row order (t*64+b)
__global__ void k0a_convert(const float* __restrict__ in, bf16* __restrict__ xbf) {
    int o = blockIdx.x * 256 + threadIdx.x;
    int k = o & 511;
    int r = o >> 9;
    int t = r >> 6, b = r & 63;
    xbf[o] = (bf16)in[(b * 512 + t) * 512 + k];
}

// ---------------- K0b: W_cat^T[c][k] bf16 (c = h*4+gate) and b_cat f32
__global__ void k0b_wcat(const float* __restrict__ Wi, const float* __restrict__ Wf,
                         const float* __restrict__ Wo, const float* __restrict__ Wc,
                         const float* __restrict__ bi, const float* __restrict__ bfv,
                         const float* __restrict__ bo, const float* __restrict__ bc,
                         bf16* __restrict__ wct, float* __restrict__ bcat) {
    int o = blockIdx.x * 256 + threadIdx.x;      // o = c*512 + k
    int k = o & 511;
    int c = o >> 9;
    int h = c >> 2, g = c & 3;
    const float* W = (g == 0) ? Wi : (g == 1) ? Wf : (g == 2) ? Wo : Wc;
    wct[o] = (bf16)W[k * 512 + h];
    if (o < 2048) {
        int hh = o >> 2, gg = o & 3;
        const float* bv = (gg == 0) ? bi : (gg == 1) ? bfv : (gg == 2) ? bo : bc;
        bcat[o] = bv[hh];
    }
}

// ---------------- K0c: U pre-swizzled into B-fragment order for phase 2.
__global__ void k0c_uswz(const float* __restrict__ Ui, const float* __restrict__ Uf,
                         const float* __restrict__ Uo, const float* __restrict__ Uc,
                         bf16* __restrict__ usw) {
    int o = blockIdx.x * 256 + threadIdx.x;      // [0, 1048576)
    int e  = o & 7;
    int l  = (o >> 3) & 63;
    int ks = (o >> 9) & 15;
    int nt = (o >> 13) & 1;
    int w  = (o >> 14) & 3;
    int s  = o >> 16;
    int k = ks * 32 + (l >> 4) * 8 + e;
    int col_local = (2 * w + nt) * 16 + (l & 15);
    int h = s * 32 + (col_local >> 2);
    int g = col_local & 3;
    const float* U = (g == 0) ? Ui : (g == 1) ? Uf : (g == 2) ? Uo : Uc;
    usw[o] = (bf16)U[k * 512 + h];
}

// ---------------- K1: xp = x_bf @ W_cat + b_cat   (bf16 out)
__launch_bounds__(256, 2)
__global__ void k1_gemm(const bf16* __restrict__ xbf, const bf16* __restrict__ wct,
                        const float* __restrict__ bcat, bf16* __restrict__ xp) {
    __shared__ bf16 As[128 * 40];
    __shared__ bf16 Bs[128 * 40];
    int tid = threadIdx.x;
    int wid = tid >> 6, lane = tid & 63;
    int q = lane >> 4, m = lane & 15;
    int wr = wid >> 1, wc = wid & 1;
    int br = blockIdx.x & 255, bc = blockIdx.x >> 8;

    floatx4 acc[4][4] = {};

    for (int kk = 0; kk < 16; ++kk) {
        #pragma unroll
        for (int cc = 0; cc < 2; ++cc) {
            int ch = tid + cc * 256;
            int row = ch >> 2, part = ch & 3;
            bf16x8 va = *(const bf16x8*)&xbf[(br * 128 + row) * 512 + kk * 32 + part * 8];
            bf16x8 vb = *(const bf16x8*)&wct[(bc * 128 + row) * 512 + kk * 32 + part * 8];
            *(bf16x8*)&As[row * 40 + part * 8] = va;
            *(bf16x8*)&Bs[row * 40 + part * 8] = vb;
        }
        __syncthreads();
        bf16x8 af[4], bfr[4];
        #pragma unroll
        for (int i = 0; i < 4; ++i) {
            af[i]  = *(const bf16x8*)&As[(wr * 64 + i * 16 + m) * 40 + q * 8];
            bfr[i] = *(const bf16x8*)&Bs[(wc * 64 + i * 16 + m) * 40 + q * 8];
        }
        #pragma unroll
        for (int mt = 0; mt < 4; ++mt)
            #pragma unroll
            for (int nt = 0; nt < 4; ++nt)
                acc[mt][nt] = __builtin_amdgcn_mfma_f32_16x16x32_bf16(
                    af[mt], bfr[nt], acc[mt][nt], 0, 0, 0);
        __syncthreads();
    }
    #pragma unroll
    for (int nt = 0; nt < 4; ++nt) {
        int C = bc * 128 + wc * 64 + nt * 16 + m;
        float bias = bcat[C];
        #pragma unroll
        for (int mt = 0; mt < 4; ++mt) {
            #pragma unroll
            for (int r = 0; r < 4; ++r) {
                int R = br * 128 + wr * 64 + mt * 16 + q * 4 + r;
                xp[(long)R * 2048 + C] = (bf16)(acc[mt][nt][r] + bias);
            }
        }
    }
}

// ---------------- K2: persistent recurrence.
// 64 blocks x 256 threads. block = (bg = blockIdx&3, s = blockIdx>>2).
// h exchange: hbuf32 u32[2][4][16][256] (packed bf16 pairs), write-through
// agent atomics; flags relaxed (ordering from __syncthreads vmcnt drain).
__launch_bounds__(256, 1)
__global__ void k2_rec(const bf16* __restrict__ xp, const bf16* __restrict__ usw,
                       uint32_t* __restrict__ hbuf32, uint32_t* __restrict__ flags,
                       float* __restrict__ out) {
    __shared__ float g_lds[128 * 21];             // [col_local][row], pad 16->21

    int tid = threadIdx.x;
    int wid = tid >> 6, lane = tid & 63;
    int q = lane >> 4, m = lane & 15;
    int bg = blockIdx.x & 3, s = blockIdx.x >> 2;

    // U B-fragments in registers (one-time, reused all 512 steps)
    bf16x8 bfr[2][16];
    {
        const bf16x8* base = (const bf16x8*)usw;
        #pragma unroll
        for (int nt = 0; nt < 2; ++nt)
            #pragma unroll
            for (int ks = 0; ks < 16; ++ks)
                bfr[nt][ks] = base[(((s * 4 + wid) * 2 + nt) * 16 + ks) * 64 + lane];
    }

    // gate-thread mapping: batch row r (0..15), hidden cols jc, jc+1
    int r = tid >> 4;
    int jc = (tid & 15) * 2;
    float cs0 = 0.f, cs1 = 0.f;

    uint32_t* gflags = flags + bg * 16;

    for (int t = 0; t < T_STEPS; ++t) {
        // xp prefetch (C-frag layout), independent of h — overlaps the poll
        float xpv[2][4];
        #pragma unroll
        for (int nt = 0; nt < 2; ++nt) {
            int Cg = s * 128 + (2 * wid + nt) * 16 + m;
            #pragma unroll
            for (int rr = 0; rr < 4; ++rr) {
                int R = t * 64 + bg * 16 + q * 4 + rr;
                xpv[nt][rr] = (float)xp[(long)R * 2048 + Cg];
            }
        }
        floatx4 acc[2];
        #pragma unroll
        for (int nt = 0; nt < 2; ++nt) {
            acc[nt][0] = xpv[nt][0]; acc[nt][1] = xpv[nt][1];
            acc[nt][2] = xpv[nt][2]; acc[nt][3] = xpv[nt][3];
        }

        if (t > 0) {
            // wait for all 16 slices of this batch group to publish h_{t-1}
            uint32_t tgt = (uint32_t)t;
            while (true) {
                uint32_t v = 0xFFFFFFFFu;
                if (lane < 16)
                    v = __hip_atomic_load(&gflags[lane], __ATOMIC_RELAXED,
                                          __HIP_MEMORY_SCOPE_AGENT);
                if (__all((int)(v >= tgt))) break;
                __builtin_amdgcn_s_sleep(1);
            }
            __atomic_signal_fence(__ATOMIC_ACQ_REL);

            // h_{t-1} A-frags straight from global via agent atomic u64 loads
            const u64* hp = (const u64*)(hbuf32 + ((((t - 1) & 1) * 4 + bg) << 12));
            bf16x8 af[16];
            #pragma unroll
            for (int ks = 0; ks < 16; ++ks) {
                const u64* p = hp + (m * 128 + ks * 8 + q * 2); // elem/4
                union { u64 u[2]; bf16x8 v; } cv;
                cv.u[0] = __hip_atomic_load(p, __ATOMIC_RELAXED,
                                            __HIP_MEMORY_SCOPE_AGENT);
                cv.u[1] = __hip_atomic_load(p + 1, __ATOMIC_RELAXED,
                                            __HIP_MEMORY_SCOPE_AGENT);
                af[ks] = cv.v;
            }
            #pragma unroll
            for (int ks = 0; ks < 16; ++ks) {
                acc[0] = __builtin_amdgcn_mfma_f32_16x16x32_bf16(af[ks], bfr[0][ks], acc[0], 0, 0, 0);
                acc[1] = __builtin_amdgcn_mfma_f32_16x16x32_bf16(af[ks], bfr[1][ks], acc[1], 0, 0, 0);
            }
        }

        // scatter g to LDS: g_lds[col_local][row]
        #pragma unroll
        for (int nt = 0; nt < 2; ++nt) {
            int col = (2 * wid + nt) * 16 + m;
            *(floatx4*)&g_lds[col * 21 + q * 4] = acc[nt];
        }
        __syncthreads();

        // gates: thread handles units (r, jc) and (r, jc+1)
        uint32_t* hdst = hbuf32 + (((t & 1) * 4 + bg) << 12);
        float h0, h1;
        {
            float gi = g_lds[(jc * 4 + 0) * 21 + r];
            float gf = g_lds[(jc * 4 + 1) * 21 + r];
            float go = g_lds[(jc * 4 + 2) * 21 + r];
            float gc = g_lds[(jc * 4 + 3) * 21 + r];
            float ig = 1.f / (1.f + __expf(-gi));
            float fg = 1.f / (1.f + __expf(-gf));
            float og = 1.f / (1.f + __expf(-go));
            float th = 1.f - 2.f / (__expf(2.f * gc) + 1.f);
            cs0 = fg * cs0 + ig * th;
            h0 = og * (1.f - 2.f / (__expf(2.f * cs0) + 1.f));
        }
        {
            float gi = g_lds[((jc + 1) * 4 + 0) * 21 + r];
            float gf = g_lds[((jc + 1) * 4 + 1) * 21 + r];
            float go = g_lds[((jc + 1) * 4 + 2) * 21 + r];
            float gc = g_lds[((jc + 1) * 4 + 3) * 21 + r];
            float ig = 1.f / (1.f + __expf(-gi));
            float fg = 1.f / (1.f + __expf(-gf));
            float og = 1.f / (1.f + __expf(-go));
            float th = 1.f - 2.f / (__expf(2.f * gc) + 1.f);
            cs1 = fg * cs1 + ig * th;
            h1 = og * (1.f - 2.f / (__expf(2.f * cs1) + 1.f));
        }
        // write-through publish of packed h pair (agent scope, relaxed)
        __hip_atomic_store(&hdst[(r * 512 + s * 32 + jc) >> 1], pack_bf16x2(h0, h1),
                           __ATOMIC_RELAXED, __HIP_MEMORY_SCOPE_AGENT);
        if (t == T_STEPS - 1) {
            out[(bg * 16 + r) * 512 + s * 32 + jc]     = h0;
            out[(bg * 16 + r) * 512 + s * 32 + jc + 1] = h1;
        }
        __syncthreads();   // drains vmcnt(0): h stores are at the coherence point

        if (tid == 0)
            __hip_atomic_store(&gflags[s], (uint32_t)(t + 1), __ATOMIC_RELAXED,
                               __HIP_MEMORY_SCOPE_AGENT);
    }
}

// ---------------------------------------------------------------------------
extern "C" void kernel_launch(void* const* d_in, const int* in_sizes, int n_in,
                              void* d_out, int out_size, void* d_ws, size_t ws_size,
                              hipStream_t stream) {
    const float* inp = (const float*)d_in[0];
    const float* Wi  = (const float*)d_in[1];
    const float* Wf  = (const float*)d_in[2];
    const float* Wo  = (const float*)d_in[3];
    const float* Wc  = (const float*)d_in[4];
    const float* Ui  = (const float*)d_in[5];
    const float* Uf  = (const float*)d_in[6];
    const float* Uo  = (const float*)d_in[7];
    const float* Uc  = (const float*)d_in[8];
    const float* bi  = (const float*)d_in[9];
    const float* bfv = (const float*)d_in[10];
    const float* bo  = (const float*)d_in[11];
    const float* bc  = (const float*)d_in[12];

    char* ws = (char*)d_ws;
    bf16*  xp    = (bf16*)(ws + XP_OFF);
    bf16*  xbf   = (bf16*)(ws + XBF_OFF);
    bf16*  wct   = (bf16*)(ws + WCT_OFF);
    bf16*  usw   = (bf16*)(ws + USW_OFF);
    float* bcat  = (float*)(ws + BCAT_OFF);
    uint32_t* hbuf32 = (uint32_t*)(ws + HBUF_OFF);
    uint32_t* flags  = (uint32_t*)(ws + FLAGS_OFF);

    hipMemsetAsync(flags, 0, 64 * sizeof(uint32_t), stream);

    k0a_convert<<<65536, 256, 0, stream>>>(inp, xbf);
    k0b_wcat<<<4096, 256, 0, stream>>>(Wi, Wf, Wo, Wc, bi, bfv, bo, bc, wct, bcat);
    k0c_uswz<<<4096, 256, 0, stream>>>(Ui, Uf, Uo, Uc, usw);
    k1_gemm<<<4096, 256, 0, stream>>>(xbf, wct, bcat, xp);
    k2_rec<<<64, 256, 0, stream>>>(xp, usw, hbuf32, flags, (float*)d_out);
}